// Round 2
// baseline (4694.697 us; speedup 1.0000x reference)
//
#include <hip/hip_runtime.h>

#define N_PTS 262144
#define NG 128
#define GS 1024
#define FPS_PART 16

typedef __attribute__((ext_vector_type(8))) short short8;
typedef __attribute__((ext_vector_type(8))) __bf16 bf16x8;
typedef __attribute__((ext_vector_type(4))) float f32x4;

__device__ __forceinline__ unsigned short f2bf(float f) {
  unsigned u = __float_as_uint(f);
  unsigned r = u + 0x7FFFu + ((u >> 16) & 1u);
  return (unsigned short)(r >> 16);
}

__device__ __forceinline__ f32x4 mfma16(short8 a, short8 b, f32x4 c) {
  return __builtin_amdgcn_mfma_f32_16x16x32_bf16(
      __builtin_bit_cast(bf16x8, a), __builtin_bit_cast(bf16x8, b), c, 0, 0, 0);
}

__device__ __forceinline__ unsigned long long shfl_xor_u64(unsigned long long v, int m) {
  unsigned lo = __shfl_xor((unsigned)v, m);
  unsigned hi = __shfl_xor((unsigned)(v >> 32), m);
  return ((unsigned long long)hi << 32) | lo;
}

__device__ __forceinline__ void st_rlx(unsigned* p, unsigned v) {
  __hip_atomic_store(p, v, __ATOMIC_RELAXED, __HIP_MEMORY_SCOPE_AGENT);
}
__device__ __forceinline__ unsigned ld_rlx(const unsigned* p) {
  return __hip_atomic_load(p, __ATOMIC_RELAXED, __HIP_MEMORY_SCOPE_AGENT);
}

// ordered-uint encode for float (monotone for all finite floats)
__device__ __forceinline__ unsigned ordenc(float f) {
  unsigned u = __float_as_uint(f);
  return (u >> 31) ? ~u : (u | 0x80000000u);
}

__device__ __forceinline__ unsigned knn_key(float x, float y, float z, float pp,
                                            float sx, float sy, float sz, float s2) {
  float dot = __fmaf_rn(sx, x, __fmaf_rn(sy, y, __fmul_rn(sz, z)));
  float d2 = __fadd_rn(__fsub_rn(s2, __fadd_rn(dot, dot)), pp);
  return ordenc(d2);
}

// ---------------- prep: point norms + bf16 transposed weights ----------------
__global__ void __launch_bounds__(256) prep_kernel(const float* __restrict__ pc,
    const float* __restrict__ w2, const float* __restrict__ w3,
    float* __restrict__ p2, unsigned short* __restrict__ w2t,
    unsigned short* __restrict__ w3t) {
  int i = blockIdx.x * 256 + threadIdx.x;
  if (i < N_PTS) {
    float x = pc[i], y = pc[i + N_PTS], z = pc[i + 2 * N_PTS];
    p2[i] = __fadd_rn(__fadd_rn(__fmul_rn(x, x), __fmul_rn(y, y)), __fmul_rn(z, z));
  }
  if (i < 131072) { int n = i >> 7, k = i & 127; w3t[i] = f2bf(w3[k * 1024 + n]); }
  if (i < 8192)  { int n = i >> 6, k = i & 63;  w2t[i] = f2bf(w2[k * 128 + n]); }
}

// ---------------- FPS: all-to-all slot exchange, XCD-local participants ------
// flags: [0..15] centroid, [16..31] parity0, [32..47] parity1 (memset 0 each call)
// slots: u32[2][16][8]: {keylo, keyhi, x, y, z, pad...}; centroid uses region 1.
__global__ void __launch_bounds__(1024) fps_kernel(const float* __restrict__ pc,
    float* __restrict__ sampled_out, unsigned* __restrict__ slots,
    unsigned* __restrict__ flags) {
  if (blockIdx.x & 7) return;  // keep bid%8==0 -> 16 blocks, likely one XCD
  const int p = blockIdx.x >> 3;
  const int tid = threadIdx.x;
  const int lane = tid & 63, wv = tid >> 6;
  const int gt = p * 1024 + tid;
  const float* xs = pc;
  const float* ys = pc + N_PTS;
  const float* zs = pc + 2 * N_PTS;
  float x[16], y[16], z[16], md[16];
  float sx = 0.f, sy = 0.f, sz = 0.f;
#pragma unroll
  for (int j = 0; j < 16; ++j) {
    int i = gt + j * 16384;
    x[j] = xs[i]; y[j] = ys[i]; z[j] = zs[i];
    sx += x[j]; sy += y[j]; sz += z[j];
  }
#pragma unroll
  for (int m = 32; m; m >>= 1) {
    sx += __shfl_xor(sx, m); sy += __shfl_xor(sy, m); sz += __shfl_xor(sz, m);
  }
  __shared__ float rs[3][16];
  __shared__ unsigned long long wkey[16];
  __shared__ unsigned long long bkS;
  __shared__ float bc[4];
  if (lane == 0) { rs[0][wv] = sx; rs[1][wv] = sy; rs[2][wv] = sz; }
  __syncthreads();
  if (tid == 0) {
    float ax = 0.f, ay = 0.f, az = 0.f;
    for (int w = 0; w < 16; ++w) { ax += rs[0][w]; ay += rs[1][w]; az += rs[2][w]; }
    unsigned* s = slots + (16 + p) * 8;
    st_rlx(s + 2, __float_as_uint(ax));
    st_rlx(s + 3, __float_as_uint(ay));
    st_rlx(s + 4, __float_as_uint(az));
    __hip_atomic_store(&flags[p], 1u, __ATOMIC_RELEASE, __HIP_MEMORY_SCOPE_AGENT);
  }
  if (wv == 0) {
    const int w = lane & 15;
    while (true) {
      unsigned f = __hip_atomic_load(&flags[w], __ATOMIC_ACQUIRE, __HIP_MEMORY_SCOPE_AGENT);
      if (__all((int)(f >= 1u))) break;
      __builtin_amdgcn_s_sleep(1);
    }
    const unsigned* s = slots + (16 + w) * 8;
    float vx = __uint_as_float(ld_rlx(s + 2));
    float vy = __uint_as_float(ld_rlx(s + 3));
    float vz = __uint_as_float(ld_rlx(s + 4));
    if (tid == 0) {
      float ax = 0.f, ay = 0.f, az = 0.f;
      for (int q = 0; q < 16; ++q) {
        ax += __shfl(vx, q); ay += __shfl(vy, q); az += __shfl(vz, q);
      }
      bc[1] = ax * (1.f / N_PTS); bc[2] = ay * (1.f / N_PTS); bc[3] = az * (1.f / N_PTS);
    }
  }
  __syncthreads();
  {
    float cx = bc[1], cy = bc[2], cz = bc[3];
#pragma unroll
    for (int j = 0; j < 16; ++j) {
      float dx = x[j] - cx, dy = y[j] - cy, dz = z[j] - cz;
      md[j] = sqrtf(dx * dx + dy * dy + dz * dz);
    }
  }
  for (int sel = 0; sel < NG; ++sel) {
    unsigned long long lkey = 0ull;
    int jb = 0;
#pragma unroll
    for (int j = 0; j < 16; ++j) {
      unsigned fb = __float_as_uint(md[j]);
      unsigned long long k =
          ((unsigned long long)fb << 32) | (unsigned)(~(gt + j * 16384));
      if (k > lkey) { lkey = k; jb = j; }
    }
    unsigned long long rk = lkey;
#pragma unroll
    for (int m = 32; m; m >>= 1) {
      unsigned long long o = shfl_xor_u64(rk, m);
      if (o > rk) rk = o;
    }
    if (lane == 0) wkey[wv] = rk;
    __syncthreads();
    if (tid == 0) {
      unsigned long long bk = 0ull;
      for (int w = 0; w < 16; ++w) if (wkey[w] > bk) bk = wkey[w];
      bkS = bk;
    }
    __syncthreads();
    unsigned long long bk = bkS;
    if (lkey == bk) {  // unique winner thread in this block
      unsigned* s = slots + ((sel & 1) * 16 + p) * 8;
      st_rlx(s + 0, (unsigned)(bk & 0xFFFFFFFFull));
      st_rlx(s + 1, (unsigned)(bk >> 32));
      st_rlx(s + 2, __float_as_uint(x[jb]));
      st_rlx(s + 3, __float_as_uint(y[jb]));
      st_rlx(s + 4, __float_as_uint(z[jb]));
      __hip_atomic_store(&flags[16 + (sel & 1) * 16 + p], sel + 1u, __ATOMIC_RELEASE,
                         __HIP_MEMORY_SCOPE_AGENT);
    }
    if (wv == 0) {
      const int w = lane & 15;
      unsigned* fl = &flags[16 + (sel & 1) * 16 + w];
      while (true) {
        unsigned f = __hip_atomic_load(fl, __ATOMIC_ACQUIRE, __HIP_MEMORY_SCOPE_AGENT);
        if (__all((int)(f >= sel + 1u))) break;
        __builtin_amdgcn_s_sleep(1);
      }
      const unsigned* s = slots + ((sel & 1) * 16 + w) * 8;
      unsigned lo = ld_rlx(s + 0), hi = ld_rlx(s + 1);
      float wx = __uint_as_float(ld_rlx(s + 2));
      float wy = __uint_as_float(ld_rlx(s + 3));
      float wz = __uint_as_float(ld_rlx(s + 4));
      unsigned long long sk = ((unsigned long long)hi << 32) | lo;
      unsigned long long gk = sk;
#pragma unroll
      for (int m = 8; m; m >>= 1) {
        unsigned long long o = shfl_xor_u64(gk, m);
        if (o > gk) gk = o;
      }
      if (sk == gk && lane < 16) {  // unique lane holding global winner
        bc[1] = wx; bc[2] = wy; bc[3] = wz;
        if (p == 0) {
          sampled_out[sel * 3 + 0] = wx;
          sampled_out[sel * 3 + 1] = wy;
          sampled_out[sel * 3 + 2] = wz;
        }
      }
    }
    __syncthreads();
    {
      float wx = bc[1], wy = bc[2], wz = bc[3];
#pragma unroll
      for (int j = 0; j < 16; ++j) {
        float dx = x[j] - wx, dy = y[j] - wy, dz = z[j] - wz;
        float d = sqrtf(dx * dx + dy * dy + dz * dz);
        md[j] = (sel == 0) ? d : fminf(md[j], d);
      }
    }
  }
}

// ---------------- KNN: 2 full scans (hist + compact) then LDS-local select ---
__device__ __forceinline__ void select_bucket(const unsigned* hist, int nbins,
                                              unsigned krem, unsigned* sres, int lane) {
  const int per = nbins >> 6;
  unsigned local = 0;
  for (int j = 0; j < per; ++j) local += hist[lane * per + j];
  unsigned inc = local;
  for (int off = 1; off < 64; off <<= 1) {
    unsigned v = __shfl_up(inc, off);
    if (lane >= off) inc += v;
  }
  unsigned exc = inc - local;
  if (exc < krem && krem <= inc) {
    unsigned c = exc;
    for (int j = 0; j < per; ++j) {
      unsigned h = hist[lane * per + j];
      if (c + h >= krem) { sres[0] = (unsigned)(lane * per + j); sres[1] = c; break; }
      c += h;
    }
  }
}

__global__ void __launch_bounds__(1024) knn_kernel(const float* __restrict__ pc,
    const float* __restrict__ p2, const float* __restrict__ sampled,
    int* __restrict__ knn) {
  const int g = blockIdx.x;
  const int tid = threadIdx.x;
  const int lane = tid & 63;
  __shared__ unsigned hist[2048];
  __shared__ unsigned candk[8192];
  __shared__ unsigned candi[8192];
  __shared__ unsigned sres[2];
  __shared__ unsigned scnt[4];
  const float* xs = pc;
  const float* ys = pc + N_PTS;
  const float* zs = pc + 2 * N_PTS;
  const float sx = sampled[g * 3 + 0], sy = sampled[g * 3 + 1], sz = sampled[g * 3 + 2];
  const float s2 = __fadd_rn(__fadd_rn(__fmul_rn(sx, sx), __fmul_rn(sy, sy)),
                             __fmul_rn(sz, sz));
  for (int i = tid; i < 2048; i += 1024) hist[i] = 0u;
  if (tid == 0) { scnt[0] = 0u; scnt[1] = 0u; scnt[2] = 0u; scnt[3] = 0u; }
  __syncthreads();
  for (int i = tid; i < N_PTS; i += 1024) {
    unsigned k = knn_key(xs[i], ys[i], zs[i], p2[i], sx, sy, sz, s2);
    atomicAdd(&hist[k >> 21], 1u);
  }
  __syncthreads();
  if (tid < 64) select_bucket(hist, 2048, GS, sres, lane);
  __syncthreads();
  const unsigned b0 = sres[0];
  unsigned krem = GS - sres[1];
  __syncthreads();
  // compact candidates (bucket == b0); emit bucket < b0 directly
  for (int i = tid; i < N_PTS; i += 1024) {
    unsigned k = knn_key(xs[i], ys[i], zs[i], p2[i], sx, sy, sz, s2);
    unsigned b = k >> 21;
    if (b < b0) {
      unsigned pos = atomicAdd(&scnt[0], 1u);
      knn[g * GS + pos] = i;
    } else if (b == b0) {
      unsigned e = atomicAdd(&scnt[1], 1u);
      if (e < 8192u) { candk[e] = k; candi[e] = i; }
    }
  }
  __syncthreads();
  const int m = (int)min(scnt[1], 8192u);
  const int base1 = (int)scnt[0];
  // level 2: bits 20..10 of candidate keys
  for (int i = tid; i < 2048; i += 1024) hist[i] = 0u;
  __syncthreads();
  for (int j = tid; j < m; j += 1024) atomicAdd(&hist[(candk[j] >> 10) & 2047u], 1u);
  __syncthreads();
  if (tid < 64) select_bucket(hist, 2048, krem, sres, lane);
  __syncthreads();
  const unsigned b2 = sres[0];
  krem -= sres[1];
  __syncthreads();
  // level 3: bits 9..0
  if (tid < 1024) hist[tid] = 0u;
  __syncthreads();
  for (int j = tid; j < m; j += 1024)
    if (((candk[j] >> 10) & 2047u) == b2) atomicAdd(&hist[candk[j] & 1023u], 1u);
  __syncthreads();
  if (tid < 64) select_bucket(hist, 1024, krem, sres, lane);
  __syncthreads();
  const unsigned b3 = sres[0];
  krem -= sres[1];
  const unsigned T = (b0 << 21) | (b2 << 10) | b3;
  __syncthreads();  // hist reads done; reuse as tie buffer
  for (int j = tid; j < m; j += 1024) {
    unsigned k = candk[j];
    if (k < T) {
      unsigned pos = atomicAdd(&scnt[2], 1u);
      knn[g * GS + base1 + (int)pos] = candi[j];
    } else if (k == T) {
      unsigned e = atomicAdd(&scnt[3], 1u);
      if (e < 2048u) hist[e] = candi[j];
    }
  }
  __syncthreads();
  if (tid < 64) {
    const int tc = (int)min(scnt[3], 2048u);
    const int base2 = base1 + (int)scnt[2];
    for (int j = 0; j < (int)krem; ++j) {
      int best = 0x7FFFFFFF;
      for (int q = lane; q < tc; q += 64) best = min(best, (int)hist[q]);
      for (int mm = 32; mm; mm >>= 1) best = min(best, __shfl_xor(best, mm));
      for (int q = lane; q < tc; q += 64)
        if ((int)hist[q] == best) hist[q] = 0x7FFFFFFFu;
      if (lane == 0) knn[g * GS + base2 + j] = best;
    }
  }
}

// ---------------- fused MLP (3->64->128->1024) + max-pool, bf16 MFMA ---------
__global__ void __launch_bounds__(256, 2) mlp_kernel(const float* __restrict__ pc,
    const int* __restrict__ knn, const float* __restrict__ w1,
    const unsigned short* __restrict__ w2t, const unsigned short* __restrict__ w3t,
    unsigned* __restrict__ gout) {
  const int blk = blockIdx.x, g = blk >> 2, split = blk & 3;
  const int tid = threadIdx.x, lane = tid & 63, wv = tid >> 6;
  __shared__ unsigned gmax[1024];
  __shared__ __align__(16) short h1[128 * 72];
  __shared__ __align__(16) short h2[128 * 136];
  __shared__ float cxs[128], cys[128], czs[128];
  for (int i = tid; i < 1024; i += 256) gmax[i] = 0u;
  const float* xs = pc;
  const float* ys = pc + N_PTS;
  const float* zs = pc + 2 * N_PTS;
  const int ch = tid & 63;
  const int pgrp = tid >> 6;
  const float w10 = w1[ch], w11 = w1[64 + ch], w12 = w1[128 + ch];
  const int r0 = (lane >> 4) * 4;
  const int cB = lane & 15;
  const int kB = (lane >> 4) * 8;
  for (int tile = 0; tile < 2; ++tile) {
    __syncthreads();
    if (tid < 128) {
      int i = knn[g * 1024 + split * 256 + tile * 128 + tid];
      cxs[tid] = xs[i]; cys[tid] = ys[i]; czs[tid] = zs[i];
    }
    __syncthreads();
    for (int q = 0; q < 32; ++q) {
      int p = pgrp * 32 + q;
      float v = fmaxf(__fmaf_rn(cxs[p], w10, __fmaf_rn(cys[p], w11, czs[p] * w12)), 0.f);
      h1[p * 72 + ch] = (short)f2bf(v);
    }
    __syncthreads();
    {
      short8 a[2][2];
#pragma unroll
      for (int mt = 0; mt < 2; ++mt)
#pragma unroll
        for (int ks = 0; ks < 2; ++ks)
          a[mt][ks] = *(const short8*)&h1[((2 * wv + mt) * 16 + cB) * 72 + kB + ks * 32];
#pragma unroll
      for (int n0 = 0; n0 < 8; ++n0) {
        short8 bb[2];
#pragma unroll
        for (int ks = 0; ks < 2; ++ks)
          bb[ks] = *(const short8*)&w2t[(n0 * 16 + cB) * 64 + kB + ks * 32];
#pragma unroll
        for (int mt = 0; mt < 2; ++mt) {
          f32x4 acc = {0.f, 0.f, 0.f, 0.f};
          acc = mfma16(a[mt][0], bb[0], acc);
          acc = mfma16(a[mt][1], bb[1], acc);
          int rr = (2 * wv + mt) * 16 + r0;
#pragma unroll
          for (int r = 0; r < 4; ++r)
            h2[(rr + r) * 136 + n0 * 16 + cB] = (short)f2bf(fmaxf(acc[r], 0.f));
        }
      }
    }
    __syncthreads();
    {
      short8 a2[2][4];
#pragma unroll
      for (int mt = 0; mt < 2; ++mt)
#pragma unroll
        for (int ks = 0; ks < 4; ++ks)
          a2[mt][ks] = *(const short8*)&h2[((2 * wv + mt) * 16 + cB) * 136 + kB + ks * 32];
      for (int n0 = 0; n0 < 64; ++n0) {
        short8 b3[4];
#pragma unroll
        for (int ks = 0; ks < 4; ++ks)
          b3[ks] = *(const short8*)&w3t[(n0 * 16 + cB) * 128 + kB + ks * 32];
        f32x4 acc0 = {0.f, 0.f, 0.f, 0.f}, acc1 = {0.f, 0.f, 0.f, 0.f};
#pragma unroll
        for (int ks = 0; ks < 4; ++ks) acc0 = mfma16(a2[0][ks], b3[ks], acc0);
#pragma unroll
        for (int ks = 0; ks < 4; ++ks) acc1 = mfma16(a2[1][ks], b3[ks], acc1);
        float mv = fmaxf(fmaxf(fmaxf(acc0[0], acc0[1]), fmaxf(acc0[2], acc0[3])),
                         fmaxf(fmaxf(acc1[0], acc1[1]), fmaxf(acc1[2], acc1[3])));
        mv = fmaxf(mv, __shfl_xor(mv, 16));
        mv = fmaxf(mv, __shfl_xor(mv, 32));
        if (lane < 16) atomicMax(&gmax[n0 * 16 + lane], ordenc(mv));
      }
    }
  }
  __syncthreads();
  for (int i = tid; i < 1024; i += 256)
    gout[(g * 4 + split) * 1024 + i] = gmax[i];
}

// ---------------- combine split partials -> d_out ----------------------------
__global__ void __launch_bounds__(256) combine_kernel(const unsigned* __restrict__ gm,
                                                      float* __restrict__ out) {
  int c = blockIdx.x * 256 + threadIdx.x;
  int g = c >> 10, chn = c & 1023;
  unsigned m = 0u;
#pragma unroll
  for (int s = 0; s < 4; ++s) {
    unsigned v = gm[(g * 4 + s) * 1024 + chn];
    if (v > m) m = v;
  }
  out[c] = (m >> 31) ? __uint_as_float(m ^ 0x80000000u) : __uint_as_float(~m);
}

extern "C" void kernel_launch(void* const* d_in, const int* in_sizes, int n_in,
                              void* d_out, int out_size, void* d_ws, size_t ws_size,
                              hipStream_t stream) {
  (void)in_sizes; (void)n_in; (void)out_size; (void)ws_size;
  const float* pc = (const float*)d_in[0];
  const float* w1 = (const float*)d_in[1];
  const float* w2 = (const float*)d_in[2];
  const float* w3 = (const float*)d_in[3];
  float* out = (float*)d_out;
  char* ws = (char*)d_ws;

  unsigned* flags = (unsigned*)(ws + 0);       // 192 B used (memset 256)
  unsigned* slots = (unsigned*)(ws + 256);     // 1 KiB
  float* p2 = (float*)(ws + 4096);             // 1 MiB
  unsigned short* w2t = (unsigned short*)(ws + 4096 + 1048576);           // 16 KiB
  unsigned short* w3t = (unsigned short*)(ws + 4096 + 1048576 + 16384);   // 256 KiB
  int* knn = (int*)(ws + 4096 + 1048576 + 16384 + 262144);                // 512 KiB
  unsigned* gout = (unsigned*)(ws + 4096 + 1048576 + 16384 + 262144 + 524288); // 2 MiB
  float* sampled = out + 131072;

  hipMemsetAsync(ws, 0, 256, stream);
  prep_kernel<<<1024, 256, 0, stream>>>(pc, w2, w3, p2, w2t, w3t);
  fps_kernel<<<121, 1024, 0, stream>>>(pc, sampled, slots, flags);
  knn_kernel<<<NG, 1024, 0, stream>>>(pc, p2, sampled, knn);
  mlp_kernel<<<NG * 4, 256, 0, stream>>>(pc, knn, w1, w2t, w3t, gout);
  combine_kernel<<<512, 256, 0, stream>>>(gout, out);
}

// Round 3
// 2031.047 us; speedup vs baseline: 2.3115x; 2.3115x over previous
//
#include <hip/hip_runtime.h>

#define N_PTS 262144
#define NG 128
#define GS 1024
#define FPS_B 16

typedef __attribute__((ext_vector_type(8))) short short8;
typedef __attribute__((ext_vector_type(8))) __bf16 bf16x8;
typedef __attribute__((ext_vector_type(4))) float f32x4;
typedef unsigned long long ull;

__device__ __forceinline__ unsigned short f2bf(float f) {
  unsigned u = __float_as_uint(f);
  unsigned r = u + 0x7FFFu + ((u >> 16) & 1u);
  return (unsigned short)(r >> 16);
}

__device__ __forceinline__ f32x4 mfma16(short8 a, short8 b, f32x4 c) {
  return __builtin_amdgcn_mfma_f32_16x16x32_bf16(
      __builtin_bit_cast(bf16x8, a), __builtin_bit_cast(bf16x8, b), c, 0, 0, 0);
}

__device__ __forceinline__ ull shfl_xor_u64(ull v, int m) {
  unsigned lo = __shfl_xor((unsigned)v, m);
  unsigned hi = __shfl_xor((unsigned)(v >> 32), m);
  return ((ull)hi << 32) | lo;
}

__device__ __forceinline__ void st64(ull* p, ull v) {
  __hip_atomic_store(p, v, __ATOMIC_RELAXED, __HIP_MEMORY_SCOPE_AGENT);
}
__device__ __forceinline__ ull ld64(const ull* p) {
  return __hip_atomic_load(p, __ATOMIC_RELAXED, __HIP_MEMORY_SCOPE_AGENT);
}

// ordered-uint encode for float (monotone for all finite floats)
__device__ __forceinline__ unsigned ordenc(float f) {
  unsigned u = __float_as_uint(f);
  return (u >> 31) ? ~u : (u | 0x80000000u);
}

__device__ __forceinline__ unsigned knn_key(float x, float y, float z, float pp,
                                            float sx, float sy, float sz, float s2) {
  float dot = __fmaf_rn(sx, x, __fmaf_rn(sy, y, __fmul_rn(sz, z)));
  float d2 = __fadd_rn(__fsub_rn(s2, __fadd_rn(dot, dot)), pp);
  return ordenc(d2);
}

// ---------------- prep: point norms + bf16 transposed weights ----------------
__global__ void __launch_bounds__(256) prep_kernel(const float* __restrict__ pc,
    const float* __restrict__ w2, const float* __restrict__ w3,
    float* __restrict__ p2, unsigned short* __restrict__ w2t,
    unsigned short* __restrict__ w3t) {
  int i = blockIdx.x * 256 + threadIdx.x;
  if (i < N_PTS) {
    float x = pc[i], y = pc[i + N_PTS], z = pc[i + 2 * N_PTS];
    p2[i] = __fadd_rn(__fadd_rn(__fmul_rn(x, x), __fmul_rn(y, y)), __fmul_rn(z, z));
  }
  if (i < 131072) { int n = i >> 7, k = i & 127; w3t[i] = f2bf(w3[k * 1024 + n]); }
  if (i < 8192)  { int n = i >> 6, k = i & 63;  w2t[i] = f2bf(w2[k * 128 + n]); }
}

// ---------------- FPS: relaxed self-validating 64-bit message exchange -------
// slots layout (ull index):
//   [par*64 + c*16 + p], par in {0,1}, c=0 key {dist:32|seq:14|~idx:18},
//   c=1..3 coords {fbits:32|seq:32}; centroid at [128 + c*16 + p], seq=0x3FFF.
__global__ void __launch_bounds__(1024) fps_kernel(const float* __restrict__ pc,
    float* __restrict__ sampled_out, ull* __restrict__ slots) {
  const int p = blockIdx.x;
  const int tid = threadIdx.x;
  const int lane = tid & 63, wv = tid >> 6;
  const int gt = p * 1024 + tid;
  const float* xs = pc;
  const float* ys = pc + N_PTS;
  const float* zs = pc + 2 * N_PTS;
  float x[16], y[16], z[16], md[16];
  float sx = 0.f, sy = 0.f, sz = 0.f;
#pragma unroll
  for (int j = 0; j < 16; ++j) {
    int i = gt + j * 16384;
    x[j] = xs[i]; y[j] = ys[i]; z[j] = zs[i];
    sx += x[j]; sy += y[j]; sz += z[j];
  }
#pragma unroll
  for (int m = 32; m; m >>= 1) {
    sx += __shfl_xor(sx, m); sy += __shfl_xor(sy, m); sz += __shfl_xor(sz, m);
  }
  __shared__ float rs[3][16];
  __shared__ ull wkey[16];
  __shared__ ull bkS;
  __shared__ float bc[3];
  if (lane == 0) { rs[0][wv] = sx; rs[1][wv] = sy; rs[2][wv] = sz; }
  __syncthreads();
  if (tid == 0) {
    float ax = 0.f, ay = 0.f, az = 0.f;
    for (int w = 0; w < 16; ++w) { ax += rs[0][w]; ay += rs[1][w]; az += rs[2][w]; }
    st64(&slots[128 + 16 + p], ((ull)__float_as_uint(ax) << 32) | 0x3FFFull);
    st64(&slots[128 + 32 + p], ((ull)__float_as_uint(ay) << 32) | 0x3FFFull);
    st64(&slots[128 + 48 + p], ((ull)__float_as_uint(az) << 32) | 0x3FFFull);
  }
  if (wv == 0) {
    const int w = lane & 15, c = lane >> 4;
    ull v = 0;
    for (;;) {
      if (c) v = ld64(&slots[128 + c * 16 + w]);
      bool ok = (c == 0) || ((unsigned)v == 0x3FFFu);
      if (__all((int)ok)) break;
      __builtin_amdgcn_s_sleep(2);
    }
    float f = __uint_as_float((unsigned)(v >> 32));
    float s = 0.f;
    for (int q = 0; q < 16; ++q) s += __shfl(f, (lane & 48) + q);  // ascending order
    if (lane == 16) bc[0] = s * (1.f / N_PTS);
    if (lane == 32) bc[1] = s * (1.f / N_PTS);
    if (lane == 48) bc[2] = s * (1.f / N_PTS);
  }
  __syncthreads();
  {
    float cx = bc[0], cy = bc[1], cz = bc[2];
#pragma unroll
    for (int j = 0; j < 16; ++j) {
      float dx = x[j] - cx, dy = y[j] - cy, dz = z[j] - cz;
      md[j] = sqrtf(dx * dx + dy * dy + dz * dz);
    }
  }
  for (int sel = 0; sel < NG; ++sel) {
    const unsigned seq = (unsigned)(sel + 1);
    ull lkey = 0ull;
    int jb = 0;
#pragma unroll
    for (int j = 0; j < 16; ++j) {
      unsigned fb = __float_as_uint(md[j]);
      ull k = ((ull)fb << 32) | ((ull)seq << 18) |
              (ull)(0x3FFFFu ^ (unsigned)(gt + j * 16384));
      if (k > lkey) { lkey = k; jb = j; }
    }
    ull rk = lkey;
#pragma unroll
    for (int m = 32; m; m >>= 1) {
      ull o = shfl_xor_u64(rk, m);
      if (o > rk) rk = o;
    }
    if (lane == 0) wkey[wv] = rk;
    __syncthreads();
    if (wv == 0) {
      ull bk = (lane < 16) ? wkey[lane] : 0ull;
#pragma unroll
      for (int m = 8; m; m >>= 1) {
        ull o = shfl_xor_u64(bk, m);
        if (o > bk) bk = o;
      }
      if (lane == 0) bkS = bk;
    }
    __syncthreads();
    if (lkey == bkS) {  // unique block-winner thread: publish key + exact coords
      const int base = (sel & 1) * 64;
      st64(&slots[base + p], lkey);
      st64(&slots[base + 16 + p], ((ull)__float_as_uint(x[jb]) << 32) | seq);
      st64(&slots[base + 32 + p], ((ull)__float_as_uint(y[jb]) << 32) | seq);
      st64(&slots[base + 48 + p], ((ull)__float_as_uint(z[jb]) << 32) | seq);
    }
    if (wv == 0) {
      const int w = lane & 15, c = lane >> 4;
      const int base = (sel & 1) * 64;
      ull v;
      for (;;) {
        v = ld64(&slots[base + c * 16 + w]);
        bool ok = (c == 0) ? ((unsigned)((v >> 18) & 0x3FFFu) == seq)
                           : ((unsigned)v == seq);
        if (__all((int)ok)) break;
        __builtin_amdgcn_s_sleep(2);
      }
      ull kk = (c == 0) ? v : 0ull;
      int ww = w;
#pragma unroll
      for (int m = 32; m; m >>= 1) {
        ull o = shfl_xor_u64(kk, m);
        int ow = __shfl_xor(ww, m);
        if (o > kk) { kk = o; ww = ow; }
      }
      if (c != 0 && w == ww) bc[c - 1] = __uint_as_float((unsigned)(v >> 32));
    }
    __syncthreads();
    {
      float wx = bc[0], wy = bc[1], wz = bc[2];
      if (p == 0 && tid == 0) {
        sampled_out[sel * 3 + 0] = wx;
        sampled_out[sel * 3 + 1] = wy;
        sampled_out[sel * 3 + 2] = wz;
      }
#pragma unroll
      for (int j = 0; j < 16; ++j) {
        float dx = x[j] - wx, dy = y[j] - wy, dz = z[j] - wz;
        float d = sqrtf(dx * dx + dy * dy + dz * dz);
        md[j] = (sel == 0) ? d : fminf(md[j], d);
      }
    }
  }
}

// ---------------- KNN: 2 full scans (hist + compact) then LDS-local select ---
__device__ __forceinline__ void select_bucket(const unsigned* hist, int nbins,
                                              unsigned krem, unsigned* sres, int lane) {
  const int per = nbins >> 6;
  unsigned local = 0;
  for (int j = 0; j < per; ++j) local += hist[lane * per + j];
  unsigned inc = local;
  for (int off = 1; off < 64; off <<= 1) {
    unsigned v = __shfl_up(inc, off);
    if (lane >= off) inc += v;
  }
  unsigned exc = inc - local;
  if (exc < krem && krem <= inc) {
    unsigned c = exc;
    for (int j = 0; j < per; ++j) {
      unsigned h = hist[lane * per + j];
      if (c + h >= krem) { sres[0] = (unsigned)(lane * per + j); sres[1] = c; break; }
      c += h;
    }
  }
}

__global__ void __launch_bounds__(1024) knn_kernel(const float* __restrict__ pc,
    const float* __restrict__ p2, const float* __restrict__ sampled,
    int* __restrict__ knn) {
  const int g = blockIdx.x;
  const int tid = threadIdx.x;
  const int lane = tid & 63;
  __shared__ unsigned hist[2048];
  __shared__ unsigned candk[8192];
  __shared__ unsigned candi[8192];
  __shared__ unsigned sres[2];
  __shared__ unsigned scnt[4];
  const float* xs = pc;
  const float* ys = pc + N_PTS;
  const float* zs = pc + 2 * N_PTS;
  const float sx = sampled[g * 3 + 0], sy = sampled[g * 3 + 1], sz = sampled[g * 3 + 2];
  const float s2 = __fadd_rn(__fadd_rn(__fmul_rn(sx, sx), __fmul_rn(sy, sy)),
                             __fmul_rn(sz, sz));
  for (int i = tid; i < 2048; i += 1024) hist[i] = 0u;
  if (tid == 0) { scnt[0] = 0u; scnt[1] = 0u; scnt[2] = 0u; scnt[3] = 0u; }
  __syncthreads();
  for (int i = tid; i < N_PTS; i += 1024) {
    unsigned k = knn_key(xs[i], ys[i], zs[i], p2[i], sx, sy, sz, s2);
    atomicAdd(&hist[k >> 21], 1u);
  }
  __syncthreads();
  if (tid < 64) select_bucket(hist, 2048, GS, sres, lane);
  __syncthreads();
  const unsigned b0 = sres[0];
  unsigned krem = GS - sres[1];
  __syncthreads();
  for (int i = tid; i < N_PTS; i += 1024) {
    unsigned k = knn_key(xs[i], ys[i], zs[i], p2[i], sx, sy, sz, s2);
    unsigned b = k >> 21;
    if (b < b0) {
      unsigned pos = atomicAdd(&scnt[0], 1u);
      knn[g * GS + pos] = i;
    } else if (b == b0) {
      unsigned e = atomicAdd(&scnt[1], 1u);
      if (e < 8192u) { candk[e] = k; candi[e] = i; }
    }
  }
  __syncthreads();
  const int m = (int)min(scnt[1], 8192u);
  const int base1 = (int)scnt[0];
  for (int i = tid; i < 2048; i += 1024) hist[i] = 0u;
  __syncthreads();
  for (int j = tid; j < m; j += 1024) atomicAdd(&hist[(candk[j] >> 10) & 2047u], 1u);
  __syncthreads();
  if (tid < 64) select_bucket(hist, 2048, krem, sres, lane);
  __syncthreads();
  const unsigned b2 = sres[0];
  krem -= sres[1];
  __syncthreads();
  if (tid < 1024) hist[tid] = 0u;
  __syncthreads();
  for (int j = tid; j < m; j += 1024)
    if (((candk[j] >> 10) & 2047u) == b2) atomicAdd(&hist[candk[j] & 1023u], 1u);
  __syncthreads();
  if (tid < 64) select_bucket(hist, 1024, krem, sres, lane);
  __syncthreads();
  const unsigned b3 = sres[0];
  krem -= sres[1];
  const unsigned T = (b0 << 21) | (b2 << 10) | b3;
  __syncthreads();
  for (int j = tid; j < m; j += 1024) {
    unsigned k = candk[j];
    if (k < T) {
      unsigned pos = atomicAdd(&scnt[2], 1u);
      knn[g * GS + base1 + (int)pos] = candi[j];
    } else if (k == T) {
      unsigned e = atomicAdd(&scnt[3], 1u);
      if (e < 2048u) hist[e] = candi[j];
    }
  }
  __syncthreads();
  if (tid < 64) {
    const int tc = (int)min(scnt[3], 2048u);
    const int base2 = base1 + (int)scnt[2];
    for (int j = 0; j < (int)krem; ++j) {
      int best = 0x7FFFFFFF;
      for (int q = lane; q < tc; q += 64) best = min(best, (int)hist[q]);
      for (int mm = 32; mm; mm >>= 1) best = min(best, __shfl_xor(best, mm));
      for (int q = lane; q < tc; q += 64)
        if ((int)hist[q] == best) hist[q] = 0x7FFFFFFFu;
      if (lane == 0) knn[g * GS + base2 + j] = best;
    }
  }
}

// ---------------- fused MLP (3->64->128->1024) + max-pool, bf16 MFMA ---------
__global__ void __launch_bounds__(256, 2) mlp_kernel(const float* __restrict__ pc,
    const int* __restrict__ knn, const float* __restrict__ w1,
    const unsigned short* __restrict__ w2t, const unsigned short* __restrict__ w3t,
    unsigned* __restrict__ gout) {
  const int blk = blockIdx.x, g = blk >> 2, split = blk & 3;
  const int tid = threadIdx.x, lane = tid & 63, wv = tid >> 6;
  __shared__ unsigned gmax[1024];
  __shared__ __align__(16) short h1[128 * 72];
  __shared__ __align__(16) short h2[128 * 136];
  __shared__ float cxs[128], cys[128], czs[128];
  for (int i = tid; i < 1024; i += 256) gmax[i] = 0u;
  const float* xs = pc;
  const float* ys = pc + N_PTS;
  const float* zs = pc + 2 * N_PTS;
  const int ch = tid & 63;
  const int pgrp = tid >> 6;
  const float w10 = w1[ch], w11 = w1[64 + ch], w12 = w1[128 + ch];
  const int r0 = (lane >> 4) * 4;
  const int cB = lane & 15;
  const int kB = (lane >> 4) * 8;
  for (int tile = 0; tile < 2; ++tile) {
    __syncthreads();
    if (tid < 128) {
      int i = knn[g * 1024 + split * 256 + tile * 128 + tid];
      cxs[tid] = xs[i]; cys[tid] = ys[i]; czs[tid] = zs[i];
    }
    __syncthreads();
    for (int q = 0; q < 32; ++q) {
      int p = pgrp * 32 + q;
      float v = fmaxf(__fmaf_rn(cxs[p], w10, __fmaf_rn(cys[p], w11, czs[p] * w12)), 0.f);
      h1[p * 72 + ch] = (short)f2bf(v);
    }
    __syncthreads();
    {
      short8 a[2][2];
#pragma unroll
      for (int mt = 0; mt < 2; ++mt)
#pragma unroll
        for (int ks = 0; ks < 2; ++ks)
          a[mt][ks] = *(const short8*)&h1[((2 * wv + mt) * 16 + cB) * 72 + kB + ks * 32];
#pragma unroll
      for (int n0 = 0; n0 < 8; ++n0) {
        short8 bb[2];
#pragma unroll
        for (int ks = 0; ks < 2; ++ks)
          bb[ks] = *(const short8*)&w2t[(n0 * 16 + cB) * 64 + kB + ks * 32];
#pragma unroll
        for (int mt = 0; mt < 2; ++mt) {
          f32x4 acc = {0.f, 0.f, 0.f, 0.f};
          acc = mfma16(a[mt][0], bb[0], acc);
          acc = mfma16(a[mt][1], bb[1], acc);
          int rr = (2 * wv + mt) * 16 + r0;
#pragma unroll
          for (int r = 0; r < 4; ++r)
            h2[(rr + r) * 136 + n0 * 16 + cB] = (short)f2bf(fmaxf(acc[r], 0.f));
        }
      }
    }
    __syncthreads();
    {
      short8 a2[2][4];
#pragma unroll
      for (int mt = 0; mt < 2; ++mt)
#pragma unroll
        for (int ks = 0; ks < 4; ++ks)
          a2[mt][ks] = *(const short8*)&h2[((2 * wv + mt) * 16 + cB) * 136 + kB + ks * 32];
      for (int n0 = 0; n0 < 64; ++n0) {
        short8 b3[4];
#pragma unroll
        for (int ks = 0; ks < 4; ++ks)
          b3[ks] = *(const short8*)&w3t[(n0 * 16 + cB) * 128 + kB + ks * 32];
        f32x4 acc0 = {0.f, 0.f, 0.f, 0.f}, acc1 = {0.f, 0.f, 0.f, 0.f};
#pragma unroll
        for (int ks = 0; ks < 4; ++ks) acc0 = mfma16(a2[0][ks], b3[ks], acc0);
#pragma unroll
        for (int ks = 0; ks < 4; ++ks) acc1 = mfma16(a2[1][ks], b3[ks], acc1);
        float mv = fmaxf(fmaxf(fmaxf(acc0[0], acc0[1]), fmaxf(acc0[2], acc0[3])),
                         fmaxf(fmaxf(acc1[0], acc1[1]), fmaxf(acc1[2], acc1[3])));
        mv = fmaxf(mv, __shfl_xor(mv, 16));
        mv = fmaxf(mv, __shfl_xor(mv, 32));
        if (lane < 16) atomicMax(&gmax[n0 * 16 + lane], ordenc(mv));
      }
    }
  }
  __syncthreads();
  for (int i = tid; i < 1024; i += 256)
    gout[(g * 4 + split) * 1024 + i] = gmax[i];
}

// ---------------- combine split partials -> d_out ----------------------------
__global__ void __launch_bounds__(256) combine_kernel(const unsigned* __restrict__ gm,
                                                      float* __restrict__ out) {
  int c = blockIdx.x * 256 + threadIdx.x;
  int g = c >> 10, chn = c & 1023;
  unsigned m = 0u;
#pragma unroll
  for (int s = 0; s < 4; ++s) {
    unsigned v = gm[(g * 4 + s) * 1024 + chn];
    if (v > m) m = v;
  }
  out[c] = (m >> 31) ? __uint_as_float(m ^ 0x80000000u) : __uint_as_float(~m);
}

extern "C" void kernel_launch(void* const* d_in, const int* in_sizes, int n_in,
                              void* d_out, int out_size, void* d_ws, size_t ws_size,
                              hipStream_t stream) {
  (void)in_sizes; (void)n_in; (void)out_size; (void)ws_size;
  const float* pc = (const float*)d_in[0];
  const float* w1 = (const float*)d_in[1];
  const float* w2 = (const float*)d_in[2];
  const float* w3 = (const float*)d_in[3];
  float* out = (float*)d_out;
  char* ws = (char*)d_ws;

  ull* slots = (ull*)(ws + 256);               // 192 ull = 1536 B
  float* p2 = (float*)(ws + 4096);             // 1 MiB
  unsigned short* w2t = (unsigned short*)(ws + 4096 + 1048576);           // 16 KiB
  unsigned short* w3t = (unsigned short*)(ws + 4096 + 1048576 + 16384);   // 256 KiB
  int* knn = (int*)(ws + 4096 + 1048576 + 16384 + 262144);                // 512 KiB
  unsigned* gout = (unsigned*)(ws + 4096 + 1048576 + 16384 + 262144 + 524288); // 2 MiB
  float* sampled = out + 131072;

  hipMemsetAsync(ws, 0, 4096, stream);
  prep_kernel<<<1024, 256, 0, stream>>>(pc, w2, w3, p2, w2t, w3t);
  fps_kernel<<<FPS_B, 1024, 0, stream>>>(pc, sampled, slots);
  knn_kernel<<<NG, 1024, 0, stream>>>(pc, p2, sampled, knn);
  mlp_kernel<<<NG * 4, 256, 0, stream>>>(pc, knn, w1, w2t, w3t, gout);
  combine_kernel<<<512, 256, 0, stream>>>(gout, out);
}

// Round 4
// 1061.658 us; speedup vs baseline: 4.4220x; 1.9131x over previous
//
#include <hip/hip_runtime.h>

#define N_PTS 262144
#define NG 128
#define GS 1024
#define FPS_B 16

typedef __attribute__((ext_vector_type(8))) short short8;
typedef __attribute__((ext_vector_type(8))) __bf16 bf16x8;
typedef __attribute__((ext_vector_type(4))) float f32x4;
typedef unsigned long long ull;

__device__ __forceinline__ unsigned short f2bf(float f) {
  unsigned u = __float_as_uint(f);
  unsigned r = u + 0x7FFFu + ((u >> 16) & 1u);
  return (unsigned short)(r >> 16);
}

__device__ __forceinline__ f32x4 mfma16(short8 a, short8 b, f32x4 c) {
  return __builtin_amdgcn_mfma_f32_16x16x32_bf16(
      __builtin_bit_cast(bf16x8, a), __builtin_bit_cast(bf16x8, b), c, 0, 0, 0);
}

__device__ __forceinline__ ull shfl_xor_u64(ull v, int m) {
  unsigned lo = __shfl_xor((unsigned)v, m);
  unsigned hi = __shfl_xor((unsigned)(v >> 32), m);
  return ((ull)hi << 32) | lo;
}

__device__ __forceinline__ void st64(ull* p, ull v) {
  __hip_atomic_store(p, v, __ATOMIC_RELAXED, __HIP_MEMORY_SCOPE_AGENT);
}
__device__ __forceinline__ ull ld64(const ull* p) {
  return __hip_atomic_load(p, __ATOMIC_RELAXED, __HIP_MEMORY_SCOPE_AGENT);
}

// ordered-uint encode for float (monotone for all finite floats)
__device__ __forceinline__ unsigned ordenc(float f) {
  unsigned u = __float_as_uint(f);
  return (u >> 31) ? ~u : (u | 0x80000000u);
}

__device__ __forceinline__ unsigned knn_key(float x, float y, float z, float pp,
                                            float sx, float sy, float sz, float s2) {
  float dot = __fmaf_rn(sx, x, __fmaf_rn(sy, y, __fmul_rn(sz, z)));
  float d2 = __fadd_rn(__fsub_rn(s2, __fadd_rn(dot, dot)), pp);
  return ordenc(d2);
}

// ---------------- prep: point norms + bf16 transposed weights ----------------
__global__ void __launch_bounds__(256) prep_kernel(const float* __restrict__ pc,
    const float* __restrict__ w2, const float* __restrict__ w3,
    float* __restrict__ p2, unsigned short* __restrict__ w2t,
    unsigned short* __restrict__ w3t) {
  int i = blockIdx.x * 256 + threadIdx.x;
  if (i < N_PTS) {
    float x = pc[i], y = pc[i + N_PTS], z = pc[i + 2 * N_PTS];
    p2[i] = __fadd_rn(__fadd_rn(__fmul_rn(x, x), __fmul_rn(y, y)), __fmul_rn(z, z));
  }
  if (i < 131072) { int n = i >> 7, k = i & 127; w3t[i] = f2bf(w3[k * 1024 + n]); }
  if (i < 8192)  { int n = i >> 6, k = i & 63;  w2t[i] = f2bf(w2[k * 128 + n]); }
}

// ---------------- FPS: atomic-max aggregation + single-line counter poll -----
// cnts[0..3]: per-parity counters; cnts[4]: centroid counter (memset 0).
// keys[par*16]: ull {seq:14|dist:32|~idx:18}, atomic-max aggregated.
// cslots[c*16+p]: centroid partial sums (raw f32 bits), read once after counter.
__global__ void __launch_bounds__(1024) fps_kernel(const float* __restrict__ pc,
    float* __restrict__ sampled_out, unsigned* __restrict__ cnts,
    ull* __restrict__ keys, ull* __restrict__ cslots) {
  const int p = blockIdx.x;
  const int tid = threadIdx.x;
  const int lane = tid & 63, wv = tid >> 6;
  const int gt = p * 1024 + tid;
  const float* xs = pc;
  const float* ys = pc + N_PTS;
  const float* zs = pc + 2 * N_PTS;
  float x[16], y[16], z[16], md[16];
  float sx = 0.f, sy = 0.f, sz = 0.f;
#pragma unroll
  for (int j = 0; j < 16; ++j) {
    int i = gt + j * 16384;
    x[j] = xs[i]; y[j] = ys[i]; z[j] = zs[i];
    sx += x[j]; sy += y[j]; sz += z[j];
  }
#pragma unroll
  for (int m = 32; m; m >>= 1) {
    sx += __shfl_xor(sx, m); sy += __shfl_xor(sy, m); sz += __shfl_xor(sz, m);
  }
  __shared__ float rs[3][16];
  __shared__ ull wkey[16];
  __shared__ ull bkS;
  __shared__ float bc[3];
  if (lane == 0) { rs[0][wv] = sx; rs[1][wv] = sy; rs[2][wv] = sz; }
  __syncthreads();
  if (tid == 0) {
    float ax = 0.f, ay = 0.f, az = 0.f;
    for (int w = 0; w < 16; ++w) { ax += rs[0][w]; ay += rs[1][w]; az += rs[2][w]; }
    st64(&cslots[0 + p], (ull)__float_as_uint(ax));
    st64(&cslots[16 + p], (ull)__float_as_uint(ay));
    st64(&cslots[32 + p], (ull)__float_as_uint(az));
    __hip_atomic_fetch_add(&cnts[4], 1u, __ATOMIC_RELEASE, __HIP_MEMORY_SCOPE_AGENT);
  }
  if (wv == 0) {
    while (__hip_atomic_load(&cnts[4], __ATOMIC_RELAXED, __HIP_MEMORY_SCOPE_AGENT) < 16u)
      __builtin_amdgcn_s_sleep(1);
    (void)__hip_atomic_load(&cnts[4], __ATOMIC_ACQUIRE, __HIP_MEMORY_SCOPE_AGENT);
    float f = 0.f;
    if (lane < 48) f = __uint_as_float((unsigned)ld64(&cslots[lane]));
    float s = 0.f;
    for (int q = 0; q < 16; ++q) s += __shfl(f, (lane & 48) + q);  // ascending order
    if (lane == 0)  bc[0] = s * (1.f / N_PTS);
    if (lane == 16) bc[1] = s * (1.f / N_PTS);
    if (lane == 32) bc[2] = s * (1.f / N_PTS);
  }
  __syncthreads();
  {
    float cx = bc[0], cy = bc[1], cz = bc[2];
#pragma unroll
    for (int j = 0; j < 16; ++j) {
      float dx = x[j] - cx, dy = y[j] - cy, dz = z[j] - cz;
      md[j] = sqrtf(dx * dx + dy * dy + dz * dz);
    }
  }
  for (int sel = 0; sel < NG; ++sel) {
    const unsigned seq = (unsigned)(sel + 1);
    ull lkey = 0ull;
#pragma unroll
    for (int j = 0; j < 16; ++j) {
      unsigned fb = __float_as_uint(md[j]);
      ull k = ((ull)fb << 32) | ((ull)seq << 18) |
              (ull)(0x3FFFFu ^ (unsigned)(gt + j * 16384));
      if (k > lkey) lkey = k;
    }
    ull rk = lkey;
#pragma unroll
    for (int m = 32; m; m >>= 1) {
      ull o = shfl_xor_u64(rk, m);
      if (o > rk) rk = o;
    }
    if (lane == 0) wkey[wv] = rk;
    __syncthreads();
    if (wv == 0) {
      ull bk = (lane < 16) ? wkey[lane] : 0ull;
#pragma unroll
      for (int m = 8; m; m >>= 1) {
        ull o = shfl_xor_u64(bk, m);
        if (o > bk) bk = o;
      }
      if (lane == 0) bkS = bk;
    }
    __syncthreads();
    if (lkey == bkS) {  // unique block-winner thread publishes
      ull pub = ((ull)seq << 50) | ((lkey >> 32) << 18) | (lkey & 0x3FFFFull);
      __hip_atomic_fetch_max(&keys[(sel & 3) * 16], pub, __ATOMIC_RELAXED,
                             __HIP_MEMORY_SCOPE_AGENT);
      __hip_atomic_fetch_add(&cnts[sel & 3], 1u, __ATOMIC_RELEASE,
                             __HIP_MEMORY_SCOPE_AGENT);
    }
    if (wv == 0) {
      const unsigned tgt = ((unsigned)(sel >> 2) + 1u) * 16u;
      while (__hip_atomic_load(&cnts[sel & 3], __ATOMIC_RELAXED,
                               __HIP_MEMORY_SCOPE_AGENT) < tgt)
        __builtin_amdgcn_s_sleep(1);
      (void)__hip_atomic_load(&cnts[sel & 3], __ATOMIC_ACQUIRE,
                              __HIP_MEMORY_SCOPE_AGENT);
      ull k = ld64(&keys[(sel & 3) * 16]);  // same addr all lanes: 1 request
      unsigned wi = 0x3FFFFu ^ (unsigned)(k & 0x3FFFFull);
      if (lane < 3) {
        float c = pc[lane * N_PTS + wi];
        bc[lane] = c;
        if (p == 0) sampled_out[sel * 3 + lane] = c;
      }
    }
    __syncthreads();
    {
      float wx = bc[0], wy = bc[1], wz = bc[2];
#pragma unroll
      for (int j = 0; j < 16; ++j) {
        float dx = x[j] - wx, dy = y[j] - wy, dz = z[j] - wz;
        float d = sqrtf(dx * dx + dy * dy + dz * dz);
        md[j] = (sel == 0) ? d : fminf(md[j], d);
      }
    }
  }
}

// ---------------- KNN: 2 full scans (hist + compact) then LDS-local select ---
__device__ __forceinline__ void select_bucket(const unsigned* hist, int nbins,
                                              unsigned krem, unsigned* sres, int lane) {
  const int per = nbins >> 6;
  unsigned local = 0;
  for (int j = 0; j < per; ++j) local += hist[lane * per + j];
  unsigned inc = local;
  for (int off = 1; off < 64; off <<= 1) {
    unsigned v = __shfl_up(inc, off);
    if (lane >= off) inc += v;
  }
  unsigned exc = inc - local;
  if (exc < krem && krem <= inc) {
    unsigned c = exc;
    for (int j = 0; j < per; ++j) {
      unsigned h = hist[lane * per + j];
      if (c + h >= krem) { sres[0] = (unsigned)(lane * per + j); sres[1] = c; break; }
      c += h;
    }
  }
}

__global__ void __launch_bounds__(1024) knn_kernel(const float* __restrict__ pc,
    const float* __restrict__ p2, const float* __restrict__ sampled,
    int* __restrict__ knn) {
  const int g = blockIdx.x;
  const int tid = threadIdx.x;
  const int lane = tid & 63;
  __shared__ unsigned hist[2048];
  __shared__ unsigned candk[8192];
  __shared__ unsigned candi[8192];
  __shared__ unsigned sres[2];
  __shared__ unsigned scnt[4];
  const float* xs = pc;
  const float* ys = pc + N_PTS;
  const float* zs = pc + 2 * N_PTS;
  const float sx = sampled[g * 3 + 0], sy = sampled[g * 3 + 1], sz = sampled[g * 3 + 2];
  const float s2 = __fadd_rn(__fadd_rn(__fmul_rn(sx, sx), __fmul_rn(sy, sy)),
                             __fmul_rn(sz, sz));
  for (int i = tid; i < 2048; i += 1024) hist[i] = 0u;
  if (tid == 0) { scnt[0] = 0u; scnt[1] = 0u; scnt[2] = 0u; scnt[3] = 0u; }
  __syncthreads();
  for (int i = tid; i < N_PTS; i += 1024) {
    unsigned k = knn_key(xs[i], ys[i], zs[i], p2[i], sx, sy, sz, s2);
    atomicAdd(&hist[k >> 21], 1u);
  }
  __syncthreads();
  if (tid < 64) select_bucket(hist, 2048, GS, sres, lane);
  __syncthreads();
  const unsigned b0 = sres[0];
  unsigned krem = GS - sres[1];
  __syncthreads();
  for (int i = tid; i < N_PTS; i += 1024) {
    unsigned k = knn_key(xs[i], ys[i], zs[i], p2[i], sx, sy, sz, s2);
    unsigned b = k >> 21;
    if (b < b0) {
      unsigned pos = atomicAdd(&scnt[0], 1u);
      knn[g * GS + pos] = i;
    } else if (b == b0) {
      unsigned e = atomicAdd(&scnt[1], 1u);
      if (e < 8192u) { candk[e] = k; candi[e] = i; }
    }
  }
  __syncthreads();
  const int m = (int)min(scnt[1], 8192u);
  const int base1 = (int)scnt[0];
  for (int i = tid; i < 2048; i += 1024) hist[i] = 0u;
  __syncthreads();
  for (int j = tid; j < m; j += 1024) atomicAdd(&hist[(candk[j] >> 10) & 2047u], 1u);
  __syncthreads();
  if (tid < 64) select_bucket(hist, 2048, krem, sres, lane);
  __syncthreads();
  const unsigned b2 = sres[0];
  krem -= sres[1];
  __syncthreads();
  if (tid < 1024) hist[tid] = 0u;
  __syncthreads();
  for (int j = tid; j < m; j += 1024)
    if (((candk[j] >> 10) & 2047u) == b2) atomicAdd(&hist[candk[j] & 1023u], 1u);
  __syncthreads();
  if (tid < 64) select_bucket(hist, 1024, krem, sres, lane);
  __syncthreads();
  const unsigned b3 = sres[0];
  krem -= sres[1];
  const unsigned T = (b0 << 21) | (b2 << 10) | b3;
  __syncthreads();
  for (int j = tid; j < m; j += 1024) {
    unsigned k = candk[j];
    if (k < T) {
      unsigned pos = atomicAdd(&scnt[2], 1u);
      knn[g * GS + base1 + (int)pos] = candi[j];
    } else if (k == T) {
      unsigned e = atomicAdd(&scnt[3], 1u);
      if (e < 2048u) hist[e] = candi[j];
    }
  }
  __syncthreads();
  if (tid < 64) {
    const int tc = (int)min(scnt[3], 2048u);
    const int base2 = base1 + (int)scnt[2];
    for (int j = 0; j < (int)krem; ++j) {
      int best = 0x7FFFFFFF;
      for (int q = lane; q < tc; q += 64) best = min(best, (int)hist[q]);
      for (int mm = 32; mm; mm >>= 1) best = min(best, __shfl_xor(best, mm));
      for (int q = lane; q < tc; q += 64)
        if ((int)hist[q] == best) hist[q] = 0x7FFFFFFFu;
      if (lane == 0) knn[g * GS + base2 + j] = best;
    }
  }
}

// ---------------- fused MLP (3->64->128->1024) + max-pool, bf16 MFMA ---------
__global__ void __launch_bounds__(256, 2) mlp_kernel(const float* __restrict__ pc,
    const int* __restrict__ knn, const float* __restrict__ w1,
    const unsigned short* __restrict__ w2t, const unsigned short* __restrict__ w3t,
    unsigned* __restrict__ gout) {
  const int blk = blockIdx.x, g = blk >> 2, split = blk & 3;
  const int tid = threadIdx.x, lane = tid & 63, wv = tid >> 6;
  __shared__ unsigned gmax[1024];
  __shared__ __align__(16) short h1[128 * 72];
  __shared__ __align__(16) short h2[128 * 136];
  __shared__ float cxs[128], cys[128], czs[128];
  for (int i = tid; i < 1024; i += 256) gmax[i] = 0u;
  const float* xs = pc;
  const float* ys = pc + N_PTS;
  const float* zs = pc + 2 * N_PTS;
  const int ch = tid & 63;
  const int pgrp = tid >> 6;
  const float w10 = w1[ch], w11 = w1[64 + ch], w12 = w1[128 + ch];
  const int r0 = (lane >> 4) * 4;
  const int cB = lane & 15;
  const int kB = (lane >> 4) * 8;
  for (int tile = 0; tile < 2; ++tile) {
    __syncthreads();
    if (tid < 128) {
      int i = knn[g * 1024 + split * 256 + tile * 128 + tid];
      cxs[tid] = xs[i]; cys[tid] = ys[i]; czs[tid] = zs[i];
    }
    __syncthreads();
    for (int q = 0; q < 32; ++q) {
      int p = pgrp * 32 + q;
      float v = fmaxf(__fmaf_rn(cxs[p], w10, __fmaf_rn(cys[p], w11, czs[p] * w12)), 0.f);
      h1[p * 72 + ch] = (short)f2bf(v);
    }
    __syncthreads();
    {
      short8 a[2][2];
#pragma unroll
      for (int mt = 0; mt < 2; ++mt)
#pragma unroll
        for (int ks = 0; ks < 2; ++ks)
          a[mt][ks] = *(const short8*)&h1[((2 * wv + mt) * 16 + cB) * 72 + kB + ks * 32];
#pragma unroll
      for (int n0 = 0; n0 < 8; ++n0) {
        short8 bb[2];
#pragma unroll
        for (int ks = 0; ks < 2; ++ks)
          bb[ks] = *(const short8*)&w2t[(n0 * 16 + cB) * 64 + kB + ks * 32];
#pragma unroll
        for (int mt = 0; mt < 2; ++mt) {
          f32x4 acc = {0.f, 0.f, 0.f, 0.f};
          acc = mfma16(a[mt][0], bb[0], acc);
          acc = mfma16(a[mt][1], bb[1], acc);
          int rr = (2 * wv + mt) * 16 + r0;
#pragma unroll
          for (int r = 0; r < 4; ++r)
            h2[(rr + r) * 136 + n0 * 16 + cB] = (short)f2bf(fmaxf(acc[r], 0.f));
        }
      }
    }
    __syncthreads();
    {
      short8 a2[2][4];
#pragma unroll
      for (int mt = 0; mt < 2; ++mt)
#pragma unroll
        for (int ks = 0; ks < 4; ++ks)
          a2[mt][ks] = *(const short8*)&h2[((2 * wv + mt) * 16 + cB) * 136 + kB + ks * 32];
      for (int n0 = 0; n0 < 64; ++n0) {
        short8 b3[4];
#pragma unroll
        for (int ks = 0; ks < 4; ++ks)
          b3[ks] = *(const short8*)&w3t[(n0 * 16 + cB) * 128 + kB + ks * 32];
        f32x4 acc0 = {0.f, 0.f, 0.f, 0.f}, acc1 = {0.f, 0.f, 0.f, 0.f};
#pragma unroll
        for (int ks = 0; ks < 4; ++ks) acc0 = mfma16(a2[0][ks], b3[ks], acc0);
#pragma unroll
        for (int ks = 0; ks < 4; ++ks) acc1 = mfma16(a2[1][ks], b3[ks], acc1);
        float mv = fmaxf(fmaxf(fmaxf(acc0[0], acc0[1]), fmaxf(acc0[2], acc0[3])),
                         fmaxf(fmaxf(acc1[0], acc1[1]), fmaxf(acc1[2], acc1[3])));
        mv = fmaxf(mv, __shfl_xor(mv, 16));
        mv = fmaxf(mv, __shfl_xor(mv, 32));
        if (lane < 16) atomicMax(&gmax[n0 * 16 + lane], ordenc(mv));
      }
    }
  }
  __syncthreads();
  for (int i = tid; i < 1024; i += 256)
    gout[(g * 4 + split) * 1024 + i] = gmax[i];
}

// ---------------- combine split partials -> d_out ----------------------------
__global__ void __launch_bounds__(256) combine_kernel(const unsigned* __restrict__ gm,
                                                      float* __restrict__ out) {
  int c = blockIdx.x * 256 + threadIdx.x;
  int g = c >> 10, chn = c & 1023;
  unsigned m = 0u;
#pragma unroll
  for (int s = 0; s < 4; ++s) {
    unsigned v = gm[(g * 4 + s) * 1024 + chn];
    if (v > m) m = v;
  }
  out[c] = (m >> 31) ? __uint_as_float(m ^ 0x80000000u) : __uint_as_float(~m);
}

extern "C" void kernel_launch(void* const* d_in, const int* in_sizes, int n_in,
                              void* d_out, int out_size, void* d_ws, size_t ws_size,
                              hipStream_t stream) {
  (void)in_sizes; (void)n_in; (void)out_size; (void)ws_size;
  const float* pc = (const float*)d_in[0];
  const float* w1 = (const float*)d_in[1];
  const float* w2 = (const float*)d_in[2];
  const float* w3 = (const float*)d_in[3];
  float* out = (float*)d_out;
  char* ws = (char*)d_ws;

  unsigned* cnts = (unsigned*)(ws + 0);        // cnts[0..4], own line
  ull* keys = (ull*)(ws + 128);                // keys[par*16], 4 lines
  ull* cslots = (ull*)(ws + 1024);             // 48 ull
  float* p2 = (float*)(ws + 4096);             // 1 MiB
  unsigned short* w2t = (unsigned short*)(ws + 4096 + 1048576);           // 16 KiB
  unsigned short* w3t = (unsigned short*)(ws + 4096 + 1048576 + 16384);   // 256 KiB
  int* knn = (int*)(ws + 4096 + 1048576 + 16384 + 262144);                // 512 KiB
  unsigned* gout = (unsigned*)(ws + 4096 + 1048576 + 16384 + 262144 + 524288); // 2 MiB
  float* sampled = out + 131072;

  hipMemsetAsync(ws, 0, 4096, stream);
  prep_kernel<<<1024, 256, 0, stream>>>(pc, w2, w3, p2, w2t, w3t);
  fps_kernel<<<FPS_B, 1024, 0, stream>>>(pc, sampled, cnts, keys, cslots);
  knn_kernel<<<NG, 1024, 0, stream>>>(pc, p2, sampled, knn);
  mlp_kernel<<<NG * 4, 256, 0, stream>>>(pc, knn, w1, w2t, w3t, gout);
  combine_kernel<<<512, 256, 0, stream>>>(gout, out);
}

// Round 5
// 943.567 us; speedup vs baseline: 4.9755x; 1.1252x over previous
//
#include <hip/hip_runtime.h>

#define N_PTS 262144
#define NG 128
#define GS 1024
#define FPS_B 16

typedef __attribute__((ext_vector_type(8))) short short8;
typedef __attribute__((ext_vector_type(8))) __bf16 bf16x8;
typedef __attribute__((ext_vector_type(4))) float f32x4;
typedef unsigned long long ull;

__device__ __forceinline__ unsigned short f2bf(float f) {
  unsigned u = __float_as_uint(f);
  unsigned r = u + 0x7FFFu + ((u >> 16) & 1u);
  return (unsigned short)(r >> 16);
}

__device__ __forceinline__ f32x4 mfma16(short8 a, short8 b, f32x4 c) {
  return __builtin_amdgcn_mfma_f32_16x16x32_bf16(
      __builtin_bit_cast(bf16x8, a), __builtin_bit_cast(bf16x8, b), c, 0, 0, 0);
}

__device__ __forceinline__ ull shfl_xor_u64(ull v, int m) {
  unsigned lo = __shfl_xor((unsigned)v, m);
  unsigned hi = __shfl_xor((unsigned)(v >> 32), m);
  return ((ull)hi << 32) | lo;
}

__device__ __forceinline__ void st64(ull* p, ull v) {
  __hip_atomic_store(p, v, __ATOMIC_RELAXED, __HIP_MEMORY_SCOPE_AGENT);
}
__device__ __forceinline__ ull ld64(const ull* p) {
  return __hip_atomic_load(p, __ATOMIC_RELAXED, __HIP_MEMORY_SCOPE_AGENT);
}

// ordered-uint encode for float (monotone for all finite floats)
__device__ __forceinline__ unsigned ordenc(float f) {
  unsigned u = __float_as_uint(f);
  return (u >> 31) ? ~u : (u | 0x80000000u);
}

__device__ __forceinline__ unsigned knn_key(float x, float y, float z, float pp,
                                            float sx, float sy, float sz, float s2) {
  float dot = __fmaf_rn(sx, x, __fmaf_rn(sy, y, __fmul_rn(sz, z)));
  float d2 = __fadd_rn(__fsub_rn(s2, __fadd_rn(dot, dot)), pp);
  return ordenc(d2);
}

// ---------------- prep: point norms + bf16 transposed weights ----------------
__global__ void __launch_bounds__(256) prep_kernel(const float* __restrict__ pc,
    const float* __restrict__ w2, const float* __restrict__ w3,
    float* __restrict__ p2, unsigned short* __restrict__ w2t,
    unsigned short* __restrict__ w3t) {
  int i = blockIdx.x * 256 + threadIdx.x;
  if (i < N_PTS) {
    float x = pc[i], y = pc[i + N_PTS], z = pc[i + 2 * N_PTS];
    p2[i] = __fadd_rn(__fadd_rn(__fmul_rn(x, x), __fmul_rn(y, y)), __fmul_rn(z, z));
  }
  if (i < 131072) { int n = i >> 7, k = i & 127; w3t[i] = f2bf(w3[k * 1024 + n]); }
  if (i < 8192)  { int n = i >> 6, k = i & 63;  w2t[i] = f2bf(w2[k * 128 + n]); }
}

// ---------------- FPS: single-line self-validating key exchange --------------
// kslots[16] (one 128B line): {seq:14|dist:32|~idx:18}, plain relaxed stores.
// cnts[4] + cslots: centroid phase only (counter + partial sums), runs once.
__global__ void __launch_bounds__(1024) fps_kernel(const float* __restrict__ pc,
    float* __restrict__ sampled_out, unsigned* __restrict__ cnts,
    ull* __restrict__ kslots, ull* __restrict__ cslots) {
  const int p = blockIdx.x;
  const int tid = threadIdx.x;
  const int lane = tid & 63, wv = tid >> 6;
  const int gt = p * 1024 + tid;
  const float* xs = pc;
  const float* ys = pc + N_PTS;
  const float* zs = pc + 2 * N_PTS;
  float x[16], y[16], z[16], md[16];
  float sx = 0.f, sy = 0.f, sz = 0.f;
#pragma unroll
  for (int j = 0; j < 16; ++j) {
    int i = gt + j * 16384;
    x[j] = xs[i]; y[j] = ys[i]; z[j] = zs[i];
    sx += x[j]; sy += y[j]; sz += z[j];
  }
#pragma unroll
  for (int m = 32; m; m >>= 1) {
    sx += __shfl_xor(sx, m); sy += __shfl_xor(sy, m); sz += __shfl_xor(sz, m);
  }
  __shared__ float rs[3][16];
  __shared__ ull wkey[16];
  __shared__ float bc[3];
  if (lane == 0) { rs[0][wv] = sx; rs[1][wv] = sy; rs[2][wv] = sz; }
  __syncthreads();
  if (tid == 0) {
    float ax = 0.f, ay = 0.f, az = 0.f;
    for (int w = 0; w < 16; ++w) { ax += rs[0][w]; ay += rs[1][w]; az += rs[2][w]; }
    st64(&cslots[0 + p], (ull)__float_as_uint(ax));
    st64(&cslots[16 + p], (ull)__float_as_uint(ay));
    st64(&cslots[32 + p], (ull)__float_as_uint(az));
    __hip_atomic_fetch_add(&cnts[4], 1u, __ATOMIC_RELEASE, __HIP_MEMORY_SCOPE_AGENT);
  }
  if (wv == 0) {
    while (__hip_atomic_load(&cnts[4], __ATOMIC_RELAXED, __HIP_MEMORY_SCOPE_AGENT) < 16u)
      __builtin_amdgcn_s_sleep(1);
    (void)__hip_atomic_load(&cnts[4], __ATOMIC_ACQUIRE, __HIP_MEMORY_SCOPE_AGENT);
    float f = 0.f;
    if (lane < 48) f = __uint_as_float((unsigned)ld64(&cslots[lane]));
    float s = 0.f;
    for (int q = 0; q < 16; ++q) s += __shfl(f, (lane & 48) + q);  // ascending order
    if (lane == 0)  bc[0] = s * (1.f / N_PTS);
    if (lane == 16) bc[1] = s * (1.f / N_PTS);
    if (lane == 32) bc[2] = s * (1.f / N_PTS);
  }
  __syncthreads();
  {
    float cx = bc[0], cy = bc[1], cz = bc[2];
#pragma unroll
    for (int j = 0; j < 16; ++j) {
      float dx = x[j] - cx, dy = y[j] - cy, dz = z[j] - cz;
      md[j] = sqrtf(dx * dx + dy * dy + dz * dz);
    }
  }
  for (int sel = 0; sel < NG; ++sel) {
    const ull seq = (ull)(sel + 1);
    // local candidate: {dist:32 | ~idx:18} (md >= 0 so uint-compare == float-compare)
    ull lkey = 0ull;
#pragma unroll
    for (int j = 0; j < 16; ++j) {
      unsigned fb = __float_as_uint(md[j]);
      ull k = ((ull)fb << 18) | (ull)(0x3FFFFu ^ (unsigned)(gt + j * 16384));
      if (k > lkey) lkey = k;
    }
#pragma unroll
    for (int m = 32; m; m >>= 1) {
      ull o = shfl_xor_u64(lkey, m);
      if (o > lkey) lkey = o;
    }
    if (lane == 0) wkey[wv] = lkey;
    __syncthreads();
    if (wv == 0) {
      ull bk = (lane < 16) ? wkey[lane] : 0ull;
#pragma unroll
      for (int m = 8; m; m >>= 1) {
        ull o = shfl_xor_u64(bk, m);
        if (o > bk) bk = o;
      }
      if (lane == 0) st64(&kslots[p], (seq << 50) | bk);  // fire-and-forget publish
      ull v = 0ull;
      for (;;) {
        if (lane < 16) v = ld64(&kslots[lane]);  // one coalesced 128B line read
        bool ok = (lane >= 16) || ((v >> 50) == seq);
        if (__all((int)ok)) break;
        __builtin_amdgcn_s_sleep(2);
      }
      ull gk = (lane < 16) ? v : 0ull;
#pragma unroll
      for (int m = 32; m; m >>= 1) {
        ull o = shfl_xor_u64(gk, m);
        if (o > gk) gk = o;
      }
      unsigned wi = 0x3FFFFu ^ (unsigned)(gk & 0x3FFFFull);
      if (lane < 3) {
        float c = pc[lane * N_PTS + wi];
        bc[lane] = c;
        if (p == 0) sampled_out[sel * 3 + lane] = c;
      }
    }
    __syncthreads();
    {
      float wx = bc[0], wy = bc[1], wz = bc[2];
#pragma unroll
      for (int j = 0; j < 16; ++j) {
        float dx = x[j] - wx, dy = y[j] - wy, dz = z[j] - wz;
        float d = sqrtf(dx * dx + dy * dy + dz * dz);
        md[j] = (sel == 0) ? d : fminf(md[j], d);
      }
    }
  }
}

// ---------------- KNN: 2 full scans (hist + compact) then LDS-local select ---
__device__ __forceinline__ void select_bucket(const unsigned* hist, int nbins,
                                              unsigned krem, unsigned* sres, int lane) {
  const int per = nbins >> 6;
  unsigned local = 0;
  for (int j = 0; j < per; ++j) local += hist[lane * per + j];
  unsigned inc = local;
  for (int off = 1; off < 64; off <<= 1) {
    unsigned v = __shfl_up(inc, off);
    if (lane >= off) inc += v;
  }
  unsigned exc = inc - local;
  if (exc < krem && krem <= inc) {
    unsigned c = exc;
    for (int j = 0; j < per; ++j) {
      unsigned h = hist[lane * per + j];
      if (c + h >= krem) { sres[0] = (unsigned)(lane * per + j); sres[1] = c; break; }
      c += h;
    }
  }
}

__global__ void __launch_bounds__(1024) knn_kernel(const float* __restrict__ pc,
    const float* __restrict__ p2, const float* __restrict__ sampled,
    int* __restrict__ knn) {
  const int g = blockIdx.x;
  const int tid = threadIdx.x;
  const int lane = tid & 63;
  __shared__ unsigned hist[2048];
  __shared__ unsigned candk[8192];
  __shared__ unsigned candi[8192];
  __shared__ unsigned sres[2];
  __shared__ unsigned scnt[4];
  const float* xs = pc;
  const float* ys = pc + N_PTS;
  const float* zs = pc + 2 * N_PTS;
  const float sx = sampled[g * 3 + 0], sy = sampled[g * 3 + 1], sz = sampled[g * 3 + 2];
  const float s2 = __fadd_rn(__fadd_rn(__fmul_rn(sx, sx), __fmul_rn(sy, sy)),
                             __fmul_rn(sz, sz));
  for (int i = tid; i < 2048; i += 1024) hist[i] = 0u;
  if (tid == 0) { scnt[0] = 0u; scnt[1] = 0u; scnt[2] = 0u; scnt[3] = 0u; }
  __syncthreads();
  for (int i = tid; i < N_PTS; i += 1024) {
    unsigned k = knn_key(xs[i], ys[i], zs[i], p2[i], sx, sy, sz, s2);
    atomicAdd(&hist[k >> 21], 1u);
  }
  __syncthreads();
  if (tid < 64) select_bucket(hist, 2048, GS, sres, lane);
  __syncthreads();
  const unsigned b0 = sres[0];
  unsigned krem = GS - sres[1];
  __syncthreads();
  for (int i = tid; i < N_PTS; i += 1024) {
    unsigned k = knn_key(xs[i], ys[i], zs[i], p2[i], sx, sy, sz, s2);
    unsigned b = k >> 21;
    if (b < b0) {
      unsigned pos = atomicAdd(&scnt[0], 1u);
      knn[g * GS + pos] = i;
    } else if (b == b0) {
      unsigned e = atomicAdd(&scnt[1], 1u);
      if (e < 8192u) { candk[e] = k; candi[e] = i; }
    }
  }
  __syncthreads();
  const int m = (int)min(scnt[1], 8192u);
  const int base1 = (int)scnt[0];
  for (int i = tid; i < 2048; i += 1024) hist[i] = 0u;
  __syncthreads();
  for (int j = tid; j < m; j += 1024) atomicAdd(&hist[(candk[j] >> 10) & 2047u], 1u);
  __syncthreads();
  if (tid < 64) select_bucket(hist, 2048, krem, sres, lane);
  __syncthreads();
  const unsigned b2 = sres[0];
  krem -= sres[1];
  __syncthreads();
  if (tid < 1024) hist[tid] = 0u;
  __syncthreads();
  for (int j = tid; j < m; j += 1024)
    if (((candk[j] >> 10) & 2047u) == b2) atomicAdd(&hist[candk[j] & 1023u], 1u);
  __syncthreads();
  if (tid < 64) select_bucket(hist, 1024, krem, sres, lane);
  __syncthreads();
  const unsigned b3 = sres[0];
  krem -= sres[1];
  const unsigned T = (b0 << 21) | (b2 << 10) | b3;
  __syncthreads();
  for (int j = tid; j < m; j += 1024) {
    unsigned k = candk[j];
    if (k < T) {
      unsigned pos = atomicAdd(&scnt[2], 1u);
      knn[g * GS + base1 + (int)pos] = candi[j];
    } else if (k == T) {
      unsigned e = atomicAdd(&scnt[3], 1u);
      if (e < 2048u) hist[e] = candi[j];
    }
  }
  __syncthreads();
  if (tid < 64) {
    const int tc = (int)min(scnt[3], 2048u);
    const int base2 = base1 + (int)scnt[2];
    for (int j = 0; j < (int)krem; ++j) {
      int best = 0x7FFFFFFF;
      for (int q = lane; q < tc; q += 64) best = min(best, (int)hist[q]);
      for (int mm = 32; mm; mm >>= 1) best = min(best, __shfl_xor(best, mm));
      for (int q = lane; q < tc; q += 64)
        if ((int)hist[q] == best) hist[q] = 0x7FFFFFFFu;
      if (lane == 0) knn[g * GS + base2 + j] = best;
    }
  }
}

// ---------------- fused MLP (3->64->128->1024) + max-pool, bf16 MFMA ---------
__global__ void __launch_bounds__(256, 2) mlp_kernel(const float* __restrict__ pc,
    const int* __restrict__ knn, const float* __restrict__ w1,
    const unsigned short* __restrict__ w2t, const unsigned short* __restrict__ w3t,
    unsigned* __restrict__ gout) {
  const int blk = blockIdx.x, g = blk >> 2, split = blk & 3;
  const int tid = threadIdx.x, lane = tid & 63, wv = tid >> 6;
  __shared__ unsigned gmax[1024];
  __shared__ __align__(16) short h1[128 * 72];
  __shared__ __align__(16) short h2[128 * 136];
  __shared__ float cxs[128], cys[128], czs[128];
  for (int i = tid; i < 1024; i += 256) gmax[i] = 0u;
  const float* xs = pc;
  const float* ys = pc + N_PTS;
  const float* zs = pc + 2 * N_PTS;
  const int ch = tid & 63;
  const int pgrp = tid >> 6;
  const float w10 = w1[ch], w11 = w1[64 + ch], w12 = w1[128 + ch];
  const int r0 = (lane >> 4) * 4;
  const int cB = lane & 15;
  const int kB = (lane >> 4) * 8;
  for (int tile = 0; tile < 2; ++tile) {
    __syncthreads();
    if (tid < 128) {
      int i = knn[g * 1024 + split * 256 + tile * 128 + tid];
      cxs[tid] = xs[i]; cys[tid] = ys[i]; czs[tid] = zs[i];
    }
    __syncthreads();
    for (int q = 0; q < 32; ++q) {
      int p = pgrp * 32 + q;
      float v = fmaxf(__fmaf_rn(cxs[p], w10, __fmaf_rn(cys[p], w11, czs[p] * w12)), 0.f);
      h1[p * 72 + ch] = (short)f2bf(v);
    }
    __syncthreads();
    {
      short8 a[2][2];
#pragma unroll
      for (int mt = 0; mt < 2; ++mt)
#pragma unroll
        for (int ks = 0; ks < 2; ++ks)
          a[mt][ks] = *(const short8*)&h1[((2 * wv + mt) * 16 + cB) * 72 + kB + ks * 32];
#pragma unroll
      for (int n0 = 0; n0 < 8; ++n0) {
        short8 bb[2];
#pragma unroll
        for (int ks = 0; ks < 2; ++ks)
          bb[ks] = *(const short8*)&w2t[(n0 * 16 + cB) * 64 + kB + ks * 32];
#pragma unroll
        for (int mt = 0; mt < 2; ++mt) {
          f32x4 acc = {0.f, 0.f, 0.f, 0.f};
          acc = mfma16(a[mt][0], bb[0], acc);
          acc = mfma16(a[mt][1], bb[1], acc);
          int rr = (2 * wv + mt) * 16 + r0;
#pragma unroll
          for (int r = 0; r < 4; ++r)
            h2[(rr + r) * 136 + n0 * 16 + cB] = (short)f2bf(fmaxf(acc[r], 0.f));
        }
      }
    }
    __syncthreads();
    {
      short8 a2[2][4];
#pragma unroll
      for (int mt = 0; mt < 2; ++mt)
#pragma unroll
        for (int ks = 0; ks < 4; ++ks)
          a2[mt][ks] = *(const short8*)&h2[((2 * wv + mt) * 16 + cB) * 136 + kB + ks * 32];
      for (int n0 = 0; n0 < 64; ++n0) {
        short8 b3[4];
#pragma unroll
        for (int ks = 0; ks < 4; ++ks)
          b3[ks] = *(const short8*)&w3t[(n0 * 16 + cB) * 128 + kB + ks * 32];
        f32x4 acc0 = {0.f, 0.f, 0.f, 0.f}, acc1 = {0.f, 0.f, 0.f, 0.f};
#pragma unroll
        for (int ks = 0; ks < 4; ++ks) acc0 = mfma16(a2[0][ks], b3[ks], acc0);
#pragma unroll
        for (int ks = 0; ks < 4; ++ks) acc1 = mfma16(a2[1][ks], b3[ks], acc1);
        float mv = fmaxf(fmaxf(fmaxf(acc0[0], acc0[1]), fmaxf(acc0[2], acc0[3])),
                         fmaxf(fmaxf(acc1[0], acc1[1]), fmaxf(acc1[2], acc1[3])));
        mv = fmaxf(mv, __shfl_xor(mv, 16));
        mv = fmaxf(mv, __shfl_xor(mv, 32));
        if (lane < 16) atomicMax(&gmax[n0 * 16 + lane], ordenc(mv));
      }
    }
  }
  __syncthreads();
  for (int i = tid; i < 1024; i += 256)
    gout[(g * 4 + split) * 1024 + i] = gmax[i];
}

// ---------------- combine split partials -> d_out ----------------------------
__global__ void __launch_bounds__(256) combine_kernel(const unsigned* __restrict__ gm,
                                                      float* __restrict__ out) {
  int c = blockIdx.x * 256 + threadIdx.x;
  int g = c >> 10, chn = c & 1023;
  unsigned m = 0u;
#pragma unroll
  for (int s = 0; s < 4; ++s) {
    unsigned v = gm[(g * 4 + s) * 1024 + chn];
    if (v > m) m = v;
  }
  out[c] = (m >> 31) ? __uint_as_float(m ^ 0x80000000u) : __uint_as_float(~m);
}

extern "C" void kernel_launch(void* const* d_in, const int* in_sizes, int n_in,
                              void* d_out, int out_size, void* d_ws, size_t ws_size,
                              hipStream_t stream) {
  (void)in_sizes; (void)n_in; (void)out_size; (void)ws_size;
  const float* pc = (const float*)d_in[0];
  const float* w1 = (const float*)d_in[1];
  const float* w2 = (const float*)d_in[2];
  const float* w3 = (const float*)d_in[3];
  float* out = (float*)d_out;
  char* ws = (char*)d_ws;

  unsigned* cnts = (unsigned*)(ws + 0);        // centroid counter line
  ull* kslots = (ull*)(ws + 128);              // 16 ull = one 128B line
  ull* cslots = (ull*)(ws + 1024);             // 48 ull centroid partials
  float* p2 = (float*)(ws + 4096);             // 1 MiB
  unsigned short* w2t = (unsigned short*)(ws + 4096 + 1048576);           // 16 KiB
  unsigned short* w3t = (unsigned short*)(ws + 4096 + 1048576 + 16384);   // 256 KiB
  int* knn = (int*)(ws + 4096 + 1048576 + 16384 + 262144);                // 512 KiB
  unsigned* gout = (unsigned*)(ws + 4096 + 1048576 + 16384 + 262144 + 524288); // 2 MiB
  float* sampled = out + 131072;

  hipMemsetAsync(ws, 0, 4096, stream);
  prep_kernel<<<1024, 256, 0, stream>>>(pc, w2, w3, p2, w2t, w3t);
  fps_kernel<<<FPS_B, 1024, 0, stream>>>(pc, sampled, cnts, kslots, cslots);
  knn_kernel<<<NG, 1024, 0, stream>>>(pc, p2, sampled, knn);
  mlp_kernel<<<NG * 4, 256, 0, stream>>>(pc, knn, w1, w2t, w3t, gout);
  combine_kernel<<<512, 256, 0, stream>>>(gout, out);
}